// Round 1
// baseline (501.954 us; speedup 1.0000x reference)
//
#include <hip/hip_runtime.h>
#include <stdint.h>

#define NP 1024
#define NV 49408
#define ND 512
#define KPH 1024   // physical K per row: [hi(512) | lo(512)]
#define KLG 1536   // logical K: ah*bh + al*bh + ah*bl
#define BK 32
#define BM 128
#define BN 128

typedef __attribute__((ext_vector_type(8))) __bf16 bf16x8;
typedef __attribute__((ext_vector_type(4))) float f32x4;

__device__ inline unsigned long long pack_sv(float s, unsigned v) {
  unsigned u = __float_as_uint(s);
  u = (u & 0x80000000u) ? ~u : (u | 0x80000000u);  // orderable map
  return ((unsigned long long)u << 32) | (unsigned long long)v;
}

// Split each f32 row into bf16 hi/lo halves, layout [row][hi(512)|lo(512)];
// optionally emit sum of squares per row (fp32).
__global__ __launch_bounds__(256) void pack_rows_k(const float* __restrict__ src,
                                                   __bf16* __restrict__ dst,
                                                   float* __restrict__ sumsq,
                                                   int nrows) {
  int lane = threadIdx.x & 63;
  int row = blockIdx.x * 4 + (threadIdx.x >> 6);
  if (row >= nrows) return;
  const float* r = src + (size_t)row * ND + lane * 8;
  float4 x0 = *(const float4*)r;
  float4 x1 = *(const float4*)(r + 4);
  float xs[8] = {x0.x, x0.y, x0.z, x0.w, x1.x, x1.y, x1.z, x1.w};
  bf16x8 hi, lo;
  float ss = 0.f;
#pragma unroll
  for (int j = 0; j < 8; ++j) {
    float x = xs[j];
    ss += x * x;
    __bf16 h = (__bf16)x;
    hi[j] = h;
    lo[j] = (__bf16)(x - (float)h);   // exact residual, then RTNE to bf16
  }
  __bf16* drow = dst + (size_t)row * KPH + lane * 8;
  *(bf16x8*)drow = hi;
  *(bf16x8*)(drow + 512) = lo;
  if (sumsq != nullptr) {
#pragma unroll
    for (int m = 1; m < 64; m <<= 1) ss += __shfl_xor(ss, m);
    if (lane == 0) sumsq[row] = ss;
  }
}

// 128x128 tile bf16 MFMA GEMM over logical K=1536 with fused per-row argmin of
// s = b2[v] - 2*ab[p][v]. A: [NP][KPH], B: [NV][KPH] (both [hi|lo] packed).
__global__ __launch_bounds__(256) void gemm_argmin_k(const __bf16* __restrict__ A,
                                                     const __bf16* __restrict__ B,
                                                     const float* __restrict__ b2,
                                                     unsigned long long* __restrict__ best) {
  // LDS layout: [k-group g(4)][row(128)][8 bf16] -> chunk index = g*128+row
  __shared__ __bf16 tileA[4 * 128 * 8];
  __shared__ __bf16 tileB[4 * 128 * 8];

  const int tid = threadIdx.x;
  const int lane = tid & 63;
  const int wid = tid >> 6;
  const int wm = wid >> 1;       // 2 wave-rows
  const int wn = wid & 1;        // 2 wave-cols
  const int bm = blockIdx.y * BM;
  const int bn = blockIdx.x * BN;

  f32x4 acc[4][4] = {};

  for (int k0 = 0; k0 < KLG; k0 += BK) {
    // logical->physical K mapping (uniform per step):
    // A segments: [ah, al, ah] ; B segments: [bh, bh, bl]
    const int kA = (k0 < 1024) ? k0 : (k0 - 1024);
    const int kB = (k0 < 512) ? k0 : (k0 - 512);
    __syncthreads();  // previous compute done before overwrite
#pragma unroll
    for (int i = 0; i < 2; ++i) {
      int c = tid + i * 256;          // chunk id 0..511
      int g = c >> 7;                 // k-group
      int row = c & 127;              // tile row
      const __bf16* ga = A + (size_t)(bm + row) * KPH + (kA + g * 8);
      const __bf16* gb = B + (size_t)(bn + row) * KPH + (kB + g * 8);
      __builtin_amdgcn_global_load_lds((const __attribute__((address_space(1))) void*)ga,
                                       (__attribute__((address_space(3))) void*)&tileA[c * 8],
                                       16, 0, 0);
      __builtin_amdgcn_global_load_lds((const __attribute__((address_space(1))) void*)gb,
                                       (__attribute__((address_space(3))) void*)&tileB[c * 8],
                                       16, 0, 0);
    }
    __syncthreads();  // compiler drains vmcnt before barrier

    const int g = lane >> 4;
    const int r = lane & 15;
    bf16x8 a_frag[4], b_frag[4];
#pragma unroll
    for (int m = 0; m < 4; ++m)
      a_frag[m] = *(const bf16x8*)&tileA[((g << 7) + wm * 64 + m * 16 + r) * 8];
#pragma unroll
    for (int n = 0; n < 4; ++n)
      b_frag[n] = *(const bf16x8*)&tileB[((g << 7) + wn * 64 + n * 16 + r) * 8];
#pragma unroll
    for (int m = 0; m < 4; ++m)
#pragma unroll
      for (int n = 0; n < 4; ++n)
        acc[m][n] = __builtin_amdgcn_mfma_f32_16x16x32_bf16(a_frag[m], b_frag[n], acc[m][n], 0, 0, 0);
  }

  // epilogue: fused argmin. C/D map: col = lane&15, row = (lane>>4)*4 + reg.
  const int g = lane >> 4;
  const int r = lane & 15;
  float bb[4];
#pragma unroll
  for (int n = 0; n < 4; ++n) bb[n] = b2[bn + wn * 64 + n * 16 + r];

#pragma unroll
  for (int m = 0; m < 4; ++m) {
#pragma unroll
    for (int reg = 0; reg < 4; ++reg) {
      unsigned long long pk = ~0ull;
#pragma unroll
      for (int n = 0; n < 4; ++n) {
        float s = bb[n] - 2.0f * acc[m][n][reg];
        unsigned long long cand = pack_sv(s, (unsigned)(bn + wn * 64 + n * 16 + r));
        pk = (cand < pk) ? cand : pk;
      }
#pragma unroll
      for (int msk = 1; msk < 16; msk <<= 1) {
        unsigned long long o = __shfl_xor(pk, msk);
        pk = (o < pk) ? o : pk;
      }
      if (r == 0) {
        int rowg = bm + wm * 64 + m * 16 + g * 4 + reg;
        atomicMin(&best[rowg], pk);
      }
    }
  }
}

// Fallback (small ws): exact fp32 squared distance, fused argmin.
__global__ __launch_bounds__(256) void naive_argmin_k(const float* __restrict__ A,
                                                      const float* __restrict__ B,
                                                      unsigned long long* __restrict__ best) {
  __shared__ float arow[ND];
  int p = blockIdx.y;
  unsigned v = blockIdx.x * 256 + threadIdx.x;
  for (int i = threadIdx.x; i < ND; i += 256) arow[i] = A[(size_t)p * ND + i];
  __syncthreads();
  const float4* br = (const float4*)(B + (size_t)v * ND);
  float s = 0.f;
#pragma unroll 4
  for (int i = 0; i < ND / 4; ++i) {
    float4 b = br[i];
    const float4 a = *(const float4*)&arow[i * 4];
    float d0 = a.x - b.x, d1 = a.y - b.y, d2 = a.z - b.z, d3 = a.w - b.w;
    s += d0 * d0 + d1 * d1 + d2 * d2 + d3 * d3;
  }
  unsigned long long pk = pack_sv(s, v);
#pragma unroll
  for (int msk = 1; msk < 64; msk <<= 1) {
    unsigned long long o = __shfl_xor(pk, msk);
    pk = (o < pk) ? o : pk;
  }
  if ((threadIdx.x & 63) == 0) atomicMin(&best[p], pk);
}

// Gather winning rows + ids (ids written as float, d_out is read as flat f32).
__global__ __launch_bounds__(128) void gather_k(const unsigned long long* __restrict__ best,
                                                const float* __restrict__ clip,
                                                float* __restrict__ out) {
  int p = blockIdx.x;
  unsigned long long pk = best[p];
  unsigned v = (unsigned)(pk & 0xffffffffull);
  const float4* src = (const float4*)(clip + (size_t)v * ND);
  float4* dst = (float4*)(out + (size_t)p * ND);
  dst[threadIdx.x] = src[threadIdx.x];
  if (threadIdx.x == 0) out[(size_t)NP * ND + p] = (float)v;
}

extern "C" void kernel_launch(void* const* d_in, const int* in_sizes, int n_in,
                              void* d_out, int out_size, void* d_ws, size_t ws_size,
                              hipStream_t stream) {
  const float* prompt = (const float*)d_in[0];
  const float* clip = (const float*)d_in[1];
  float* out = (float*)d_out;

  // workspace layout
  size_t off = 0;
  unsigned long long* best = (unsigned long long*)d_ws;
  off += (size_t)NP * 8;                       // 8192
  float* b2 = (float*)((char*)d_ws + off);
  off += (size_t)NV * 4;                       // 197632 -> 205824 (256-aligned)
  off = (off + 255) & ~(size_t)255;
  __bf16* Ap = (__bf16*)((char*)d_ws + off);
  off += (size_t)NP * KPH * 2;                 // 2 MiB
  __bf16* Bp = (__bf16*)((char*)d_ws + off);
  off += (size_t)NV * KPH * 2;                 // ~96.5 MiB
  const size_t need = off;

  if (ws_size >= need) {
    hipMemsetAsync(best, 0xFF, (size_t)NP * 8, stream);
    pack_rows_k<<<NP / 4, 256, 0, stream>>>(prompt, Ap, nullptr, NP);
    pack_rows_k<<<NV / 4, 256, 0, stream>>>(clip, Bp, b2, NV);
    dim3 grid(NV / BN, NP / BM);  // (386, 8)
    gemm_argmin_k<<<grid, 256, 0, stream>>>(Ap, Bp, b2, best);
    gather_k<<<NP, 128, 0, stream>>>(best, clip, out);
  } else {
    // fallback: exact fp32, needs only the 8 KiB `best` array
    hipMemsetAsync(best, 0xFF, (size_t)NP * 8, stream);
    dim3 grid(NV / 256, NP);  // (193, 1024)
    naive_argmin_k<<<grid, 256, 0, stream>>>(prompt, clip, best);
    gather_k<<<NP, 128, 0, stream>>>(best, clip, out);
  }
}

// Round 2
// 417.386 us; speedup vs baseline: 1.2026x; 1.2026x over previous
//
#include <hip/hip_runtime.h>
#include <stdint.h>

#define NP 1024
#define NV 49408
#define ND 512
#define KPH 1024   // physical K per row: [hi(512) | lo(512)]
#define KLG 1536   // logical K: ah*bh + al*bh + ah*bl
#define BK 32
#define BM 128
#define BN 128

typedef __attribute__((ext_vector_type(8))) __bf16 bf16x8;
typedef __attribute__((ext_vector_type(4))) float f32x4;

__device__ inline unsigned long long pack_sv(float s, unsigned v) {
  unsigned u = __float_as_uint(s);
  u = (u & 0x80000000u) ? ~u : (u | 0x80000000u);  // orderable map
  return ((unsigned long long)u << 32) | (unsigned long long)v;
}

// Split each f32 row into bf16 hi/lo halves, layout [row][hi(512)|lo(512)];
// optionally emit sum of squares per row (fp32).
__global__ __launch_bounds__(256) void pack_rows_k(const float* __restrict__ src,
                                                   __bf16* __restrict__ dst,
                                                   float* __restrict__ sumsq,
                                                   int nrows) {
  int lane = threadIdx.x & 63;
  int row = blockIdx.x * 4 + (threadIdx.x >> 6);
  if (row >= nrows) return;
  const float* r = src + (size_t)row * ND + lane * 8;
  float4 x0 = *(const float4*)r;
  float4 x1 = *(const float4*)(r + 4);
  float xs[8] = {x0.x, x0.y, x0.z, x0.w, x1.x, x1.y, x1.z, x1.w};
  bf16x8 hi, lo;
  float ss = 0.f;
#pragma unroll
  for (int j = 0; j < 8; ++j) {
    float x = xs[j];
    ss += x * x;
    __bf16 h = (__bf16)x;
    hi[j] = h;
    lo[j] = (__bf16)(x - (float)h);   // exact residual, then RTNE to bf16
  }
  __bf16* drow = dst + (size_t)row * KPH + lane * 8;
  *(bf16x8*)drow = hi;
  *(bf16x8*)(drow + 512) = lo;
  if (sumsq != nullptr) {
#pragma unroll
    for (int m = 1; m < 64; m <<= 1) ss += __shfl_xor(ss, m);
    if (lane == 0) sumsq[row] = ss;
  }
}

// 128x128 tile bf16 MFMA GEMM over logical K=1536 with fused per-row argmin of
// s = b2[v] - 2*ab[p][v]. A: [NP][KPH], B: [NV][KPH] (both [hi|lo] packed).
// Grid: x = M-tiles (8), y = N-panels (386). x-major dispatch puts the 8
// blocks sharing one B-panel adjacent in time -> B is HBM-fetched once.
__global__ __launch_bounds__(256) void gemm_argmin_k(const __bf16* __restrict__ A,
                                                     const __bf16* __restrict__ B,
                                                     const float* __restrict__ b2,
                                                     unsigned long long* __restrict__ best) {
  // LDS layout: [k-group g(4)][row(128)][8 bf16] -> chunk index = g*128+row
  __shared__ __bf16 tileA[4 * 128 * 8];
  __shared__ __bf16 tileB[4 * 128 * 8];

  const int tid = threadIdx.x;
  const int lane = tid & 63;
  const int wid = tid >> 6;
  const int wm = wid >> 1;       // 2 wave-rows
  const int wn = wid & 1;        // 2 wave-cols
  const int bm = blockIdx.x * BM;
  const int bn = blockIdx.y * BN;

  f32x4 acc[4][4] = {};

  for (int k0 = 0; k0 < KLG; k0 += BK) {
    // logical->physical K mapping (uniform per step):
    // A segments: [ah, al, ah] ; B segments: [bh, bh, bl]
    const int kA = (k0 < 1024) ? k0 : (k0 - 1024);
    const int kB = (k0 < 512) ? k0 : (k0 - 512);
    __syncthreads();  // previous compute done before overwrite
#pragma unroll
    for (int i = 0; i < 2; ++i) {
      int c = tid + i * 256;          // chunk id 0..511
      int g = c >> 7;                 // k-group
      int row = c & 127;              // tile row
      const __bf16* ga = A + (size_t)(bm + row) * KPH + (kA + g * 8);
      const __bf16* gb = B + (size_t)(bn + row) * KPH + (kB + g * 8);
      __builtin_amdgcn_global_load_lds((const __attribute__((address_space(1))) void*)ga,
                                       (__attribute__((address_space(3))) void*)&tileA[c * 8],
                                       16, 0, 0);
      __builtin_amdgcn_global_load_lds((const __attribute__((address_space(1))) void*)gb,
                                       (__attribute__((address_space(3))) void*)&tileB[c * 8],
                                       16, 0, 0);
    }
    __syncthreads();  // compiler drains vmcnt before barrier

    const int g = lane >> 4;
    const int r = lane & 15;
    bf16x8 a_frag[4], b_frag[4];
#pragma unroll
    for (int m = 0; m < 4; ++m)
      a_frag[m] = *(const bf16x8*)&tileA[((g << 7) + wm * 64 + m * 16 + r) * 8];
#pragma unroll
    for (int n = 0; n < 4; ++n)
      b_frag[n] = *(const bf16x8*)&tileB[((g << 7) + wn * 64 + n * 16 + r) * 8];
#pragma unroll
    for (int m = 0; m < 4; ++m)
#pragma unroll
      for (int n = 0; n < 4; ++n)
        acc[m][n] = __builtin_amdgcn_mfma_f32_16x16x32_bf16(a_frag[m], b_frag[n], acc[m][n], 0, 0, 0);
  }

  // epilogue: fused argmin. C/D map: col = lane&15, row = (lane>>4)*4 + reg.
  const int g = lane >> 4;
  const int r = lane & 15;
  float bb[4];
#pragma unroll
  for (int n = 0; n < 4; ++n) bb[n] = b2[bn + wn * 64 + n * 16 + r];

#pragma unroll
  for (int m = 0; m < 4; ++m) {
#pragma unroll
    for (int reg = 0; reg < 4; ++reg) {
      unsigned long long pk = ~0ull;
#pragma unroll
      for (int n = 0; n < 4; ++n) {
        float s = bb[n] - 2.0f * acc[m][n][reg];
        unsigned long long cand = pack_sv(s, (unsigned)(bn + wn * 64 + n * 16 + r));
        pk = (cand < pk) ? cand : pk;
      }
#pragma unroll
      for (int msk = 1; msk < 16; msk <<= 1) {
        unsigned long long o = __shfl_xor(pk, msk);
        pk = (o < pk) ? o : pk;
      }
      if (r == 0) {
        int rowg = bm + wm * 64 + m * 16 + g * 4 + reg;
        atomicMin(&best[rowg], pk);
      }
    }
  }
}

// Fallback (small ws): exact fp32 squared distance, fused argmin.
__global__ __launch_bounds__(256) void naive_argmin_k(const float* __restrict__ A,
                                                      const float* __restrict__ B,
                                                      unsigned long long* __restrict__ best) {
  __shared__ float arow[ND];
  int p = blockIdx.y;
  unsigned v = blockIdx.x * 256 + threadIdx.x;
  for (int i = threadIdx.x; i < ND; i += 256) arow[i] = A[(size_t)p * ND + i];
  __syncthreads();
  const float4* br = (const float4*)(B + (size_t)v * ND);
  float s = 0.f;
#pragma unroll 4
  for (int i = 0; i < ND / 4; ++i) {
    float4 b = br[i];
    const float4 a = *(const float4*)&arow[i * 4];
    float d0 = a.x - b.x, d1 = a.y - b.y, d2 = a.z - b.z, d3 = a.w - b.w;
    s += d0 * d0 + d1 * d1 + d2 * d2 + d3 * d3;
  }
  unsigned long long pk = pack_sv(s, v);
#pragma unroll
  for (int msk = 1; msk < 64; msk <<= 1) {
    unsigned long long o = __shfl_xor(pk, msk);
    pk = (o < pk) ? o : pk;
  }
  if ((threadIdx.x & 63) == 0) atomicMin(&best[p], pk);
}

// Gather winning rows + ids (ids written as float, d_out is read as flat f32).
__global__ __launch_bounds__(128) void gather_k(const unsigned long long* __restrict__ best,
                                                const float* __restrict__ clip,
                                                float* __restrict__ out) {
  int p = blockIdx.x;
  unsigned long long pk = best[p];
  unsigned v = (unsigned)(pk & 0xffffffffull);
  const float4* src = (const float4*)(clip + (size_t)v * ND);
  float4* dst = (float4*)(out + (size_t)p * ND);
  dst[threadIdx.x] = src[threadIdx.x];
  if (threadIdx.x == 0) out[(size_t)NP * ND + p] = (float)v;
}

extern "C" void kernel_launch(void* const* d_in, const int* in_sizes, int n_in,
                              void* d_out, int out_size, void* d_ws, size_t ws_size,
                              hipStream_t stream) {
  const float* prompt = (const float*)d_in[0];
  const float* clip = (const float*)d_in[1];
  float* out = (float*)d_out;

  // workspace layout
  size_t off = 0;
  unsigned long long* best = (unsigned long long*)d_ws;
  off += (size_t)NP * 8;                       // 8192
  float* b2 = (float*)((char*)d_ws + off);
  off += (size_t)NV * 4;                       // 197632 -> 205824 (256-aligned)
  off = (off + 255) & ~(size_t)255;
  __bf16* Ap = (__bf16*)((char*)d_ws + off);
  off += (size_t)NP * KPH * 2;                 // 2 MiB
  __bf16* Bp = (__bf16*)((char*)d_ws + off);
  off += (size_t)NV * KPH * 2;                 // ~96.5 MiB
  const size_t need = off;

  if (ws_size >= need) {
    hipMemsetAsync(best, 0xFF, (size_t)NP * 8, stream);
    pack_rows_k<<<NP / 4, 256, 0, stream>>>(prompt, Ap, nullptr, NP);
    pack_rows_k<<<NV / 4, 256, 0, stream>>>(clip, Bp, b2, NV);
    dim3 grid(NP / BM, NV / BN);  // (8, 386): x = M fastest -> B-panel reuse
    gemm_argmin_k<<<grid, 256, 0, stream>>>(Ap, Bp, b2, best);
    gather_k<<<NP, 128, 0, stream>>>(best, clip, out);
  } else {
    // fallback: exact fp32, needs only the 8 KiB `best` array
    hipMemsetAsync(best, 0xFF, (size_t)NP * 8, stream);
    dim3 grid(NV / 256, NP);  // (193, 1024)
    naive_argmin_k<<<grid, 256, 0, stream>>>(prompt, clip, best);
    gather_k<<<NP, 128, 0, stream>>>(best, clip, out);
  }
}

// Round 3
// 292.732 us; speedup vs baseline: 1.7147x; 1.4258x over previous
//
#include <hip/hip_runtime.h>
#include <stdint.h>

#define NP 1024
#define NV 49408
#define ND 512
#define KPH 1024   // physical K per row: [hi(512) | lo(512)]
#define KLG 1536   // logical K: ah*bh + al*bh + ah*bl
#define NT 24      // K-tiles of 64
#define NI 12      // iterations (2 K-tiles each)

typedef __attribute__((ext_vector_type(8))) __bf16 bf16x8;
typedef __attribute__((ext_vector_type(4))) float f32x4;

__device__ inline unsigned long long pack_sv(float s, unsigned v) {
  unsigned u = __float_as_uint(s);
  u = (u & 0x80000000u) ? ~u : (u | 0x80000000u);  // orderable map
  return ((unsigned long long)u << 32) | (unsigned long long)v;
}

// Split each f32 row into bf16 hi/lo halves, layout [row][hi(512)|lo(512)];
// optionally emit sum of squares per row (fp32).
__global__ __launch_bounds__(256) void pack_rows_k(const float* __restrict__ src,
                                                   __bf16* __restrict__ dst,
                                                   float* __restrict__ sumsq,
                                                   int nrows) {
  int lane = threadIdx.x & 63;
  int row = blockIdx.x * 4 + (threadIdx.x >> 6);
  if (row >= nrows) return;
  const float* r = src + (size_t)row * ND + lane * 8;
  float4 x0 = *(const float4*)r;
  float4 x1 = *(const float4*)(r + 4);
  float xs[8] = {x0.x, x0.y, x0.z, x0.w, x1.x, x1.y, x1.z, x1.w};
  bf16x8 hi, lo;
  float ss = 0.f;
#pragma unroll
  for (int j = 0; j < 8; ++j) {
    float x = xs[j];
    ss += x * x;
    __bf16 h = (__bf16)x;
    hi[j] = h;
    lo[j] = (__bf16)(x - (float)h);   // exact residual, then RTNE to bf16
  }
  __bf16* drow = dst + (size_t)row * KPH + lane * 8;
  *(bf16x8*)drow = hi;
  *(bf16x8*)(drow + 512) = lo;
  if (sumsq != nullptr) {
#pragma unroll
    for (int m = 1; m < 64; m <<= 1) ss += __shfl_xor(ss, m);
    if (lane == 0) sumsq[row] = ss;
  }
}

// ---- 256x256 8-phase deep-pipelined GEMM + fused argmin -------------------
// LDS map (bytes): buf p in [p*65536, p*65536+65536):
//   A half kh: p*65536 + kh*16384          (256 rows x 32 cols bf16, permuted)
//   B half kh: p*65536 + 32768 + kh*16384
// 16B-slot permutation within a half: slot q holds (row,c16) with
//   q = (row>>1)*8 + (row&1)*4 + ((c16 + (row>>1)) & 3)
// -> fragment reads (16 lanes, consecutive rows, fixed c16) hit all 8
//    bank-groups (2-way aliasing = free).

__device__ __attribute__((always_inline)) static inline
void stage2(const char* src, int kByte, char* ldsDst) {
#pragma unroll
  for (int i = 0; i < 2; ++i)
    __builtin_amdgcn_global_load_lds(
        (const __attribute__((address_space(1))) void*)(src + kByte + i * 262144),
        (__attribute__((address_space(3))) void*)(ldsDst + i * 8192), 16, 0, 0);
}

template <int BP, int KH, int NH, bool VM>
__device__ __attribute__((always_inline)) static inline
void phase_op(f32x4 (&acc)[8][4], const char* aBase, const char* bBase,
              const char* sSrc, int sKByte, char* sDst) {
  // stage one half-tile (issue-early: latency hides under this phase's MFMA)
  stage2(sSrc, sKByte, sDst);
  // fragment ds_reads (10 x ds_read_b128)
  bf16x8 a[8], b[2];
#pragma unroll
  for (int m = 0; m < 8; ++m)
    a[m] = *(const bf16x8*)(aBase + BP * 65536 + KH * 16384 + m * 1024);
#pragma unroll
  for (int n = 0; n < 2; ++n)
    b[n] = *(const bf16x8*)(bBase + BP * 65536 + KH * 16384 + NH * 2048 + n * 1024);
  asm volatile("" ::: "memory");
  __builtin_amdgcn_s_barrier();
  asm volatile("" ::: "memory");
  __builtin_amdgcn_s_setprio(1);
#pragma unroll
  for (int m = 0; m < 8; ++m)
#pragma unroll
    for (int n = 0; n < 2; ++n)
      acc[m][NH * 2 + n] =
          __builtin_amdgcn_mfma_f32_16x16x32_bf16(a[m], b[n], acc[m][NH * 2 + n], 0, 0, 0);
  __builtin_amdgcn_s_setprio(0);
  if constexpr (VM) asm volatile("s_waitcnt vmcnt(4)" ::: "memory");
  asm volatile("" ::: "memory");
  __builtin_amdgcn_s_barrier();
  asm volatile("" ::: "memory");
}

__global__ __launch_bounds__(512, 2) void gemm_argmin_k(const __bf16* __restrict__ A,
                                                        const __bf16* __restrict__ B,
                                                        const float* __restrict__ b2,
                                                        unsigned long long* __restrict__ best) {
  __shared__ __align__(16) char lds[131072];
  const int tid = threadIdx.x;
  const int lane = tid & 63;
  const int wid = tid >> 6;   // 0..7
  const int wm = wid >> 2;    // 2 wave-rows (128 rows each)
  const int wn = wid & 3;     // 4 wave-cols (64 cols each)
  const int bm = blockIdx.x * 256;
  const int bn = blockIdx.y * 256;

  const int r = lane & 15, g = lane >> 4;
  const int rh = r >> 1;
  const int slot = (g + rh) & 3;
  const int laneByte = rh * 128 + (r & 1) * 64 + slot * 16;
  const char* aBase = (const char*)lds + wm * 8192 + laneByte;
  const char* bBase = (const char*)lds + 32768 + wn * 4096 + laneByte;

  // stage-side lane mapping (inverse of the slot permutation)
  const int srow0 = ((tid >> 3) << 1) | ((tid >> 2) & 1);
  const int sc16 = ((tid & 3) - (tid >> 3)) & 3;
  const char* srcA = (const char*)A + (size_t)(bm + srow0) * 2048 + sc16 * 16;
  const char* srcB = (const char*)B + (size_t)(bn + srow0) * 2048 + sc16 * 16;
  char* ldsStage = (char*)lds + tid * 16;

  f32x4 acc[8][4] = {};

  auto kAb = [](int t) { int k = t * 64; return (k < 1024 ? k : k - 1024) * 2; };
  auto kBb = [](int t) { int k = t * 64; return (k < 512 ? k : k - 512) * 2; };

  // prologue: tile0 {A0,B0,A1,B1} -> buf0 ; tile1 {A0,B0} -> buf1  (12 loads)
  stage2(srcA, kAb(0),      ldsStage + 0);
  stage2(srcB, kBb(0),      ldsStage + 32768);
  stage2(srcA, kAb(0) + 64, ldsStage + 16384);
  stage2(srcB, kBb(0) + 64, ldsStage + 49152);
  stage2(srcA, kAb(1),      ldsStage + 65536);
  stage2(srcB, kBb(1),      ldsStage + 98304);
  asm volatile("s_waitcnt vmcnt(4)" ::: "memory");   // tile0 fully resident
  __builtin_amdgcn_s_barrier();
  asm volatile("" ::: "memory");

  // 8 phases/iter; stage stream (derived death schedule):
  //  ph1:(t0+1).A1->b1  ph2:(t0+1).B1->b1  ph3:(t0+2).A0->b0  ph4:(t0+2).B0->b0 [vmcnt4]
  //  ph5:(t0+2).A1->b0  ph6:(t0+2).B1->b0  ph7:(t0+3).A0->b1  ph8:(t0+3).B0->b1 [vmcnt4]
#pragma unroll 1
  for (int it = 0; it < NI; ++it) {
    const int t0 = 2 * it, t1 = t0 + 1;
    int s2 = t0 + 2; if (s2 >= NT) s2 -= NT;   // tail wraps: reload tile0/1 (never read)
    int s3 = t0 + 3; if (s3 >= NT) s3 -= NT;
    phase_op<0, 0, 0, false>(acc, aBase, bBase, srcA, kAb(t1) + 64, ldsStage + 81920);
    phase_op<0, 0, 1, false>(acc, aBase, bBase, srcB, kBb(t1) + 64, ldsStage + 114688);
    phase_op<0, 1, 0, false>(acc, aBase, bBase, srcA, kAb(s2),      ldsStage + 0);
    phase_op<0, 1, 1, true >(acc, aBase, bBase, srcB, kBb(s2),      ldsStage + 32768);
    phase_op<1, 0, 0, false>(acc, aBase, bBase, srcA, kAb(s2) + 64, ldsStage + 16384);
    phase_op<1, 0, 1, false>(acc, aBase, bBase, srcB, kBb(s2) + 64, ldsStage + 49152);
    phase_op<1, 1, 0, false>(acc, aBase, bBase, srcA, kAb(s3),      ldsStage + 65536);
    phase_op<1, 1, 1, true >(acc, aBase, bBase, srcB, kBb(s3),      ldsStage + 98304);
  }

  // epilogue: fused argmin. C/D map: col = lane&15, row = (lane>>4)*4 + reg.
  float bb[4];
#pragma unroll
  for (int n = 0; n < 4; ++n) bb[n] = b2[bn + wn * 64 + n * 16 + r];
#pragma unroll
  for (int m = 0; m < 8; ++m) {
#pragma unroll
    for (int reg = 0; reg < 4; ++reg) {
      unsigned long long pk = ~0ull;
#pragma unroll
      for (int n = 0; n < 4; ++n) {
        float s = bb[n] - 2.0f * acc[m][n][reg];
        unsigned long long cand = pack_sv(s, (unsigned)(bn + wn * 64 + n * 16 + r));
        pk = (cand < pk) ? cand : pk;
      }
#pragma unroll
      for (int msk = 1; msk < 16; msk <<= 1) {
        unsigned long long o = __shfl_xor(pk, msk);
        pk = (o < pk) ? o : pk;
      }
      if (r == 0) atomicMin(&best[bm + wm * 128 + m * 16 + g * 4 + reg], pk);
    }
  }
}

// Fallback (small ws): exact fp32 squared distance, fused argmin.
__global__ __launch_bounds__(256) void naive_argmin_k(const float* __restrict__ A,
                                                      const float* __restrict__ B,
                                                      unsigned long long* __restrict__ best) {
  __shared__ float arow[ND];
  int p = blockIdx.y;
  unsigned v = blockIdx.x * 256 + threadIdx.x;
  for (int i = threadIdx.x; i < ND; i += 256) arow[i] = A[(size_t)p * ND + i];
  __syncthreads();
  const float4* br = (const float4*)(B + (size_t)v * ND);
  float s = 0.f;
#pragma unroll 4
  for (int i = 0; i < ND / 4; ++i) {
    float4 b = br[i];
    const float4 a = *(const float4*)&arow[i * 4];
    float d0 = a.x - b.x, d1 = a.y - b.y, d2 = a.z - b.z, d3 = a.w - b.w;
    s += d0 * d0 + d1 * d1 + d2 * d2 + d3 * d3;
  }
  unsigned long long pk = pack_sv(s, v);
#pragma unroll
  for (int msk = 1; msk < 64; msk <<= 1) {
    unsigned long long o = __shfl_xor(pk, msk);
    pk = (o < pk) ? o : pk;
  }
  if ((threadIdx.x & 63) == 0) atomicMin(&best[p], pk);
}

// Gather winning rows + ids (ids written as float, d_out is read as flat f32).
__global__ __launch_bounds__(128) void gather_k(const unsigned long long* __restrict__ best,
                                                const float* __restrict__ clip,
                                                float* __restrict__ out) {
  int p = blockIdx.x;
  unsigned long long pk = best[p];
  unsigned v = (unsigned)(pk & 0xffffffffull);
  const float4* src = (const float4*)(clip + (size_t)v * ND);
  float4* dst = (float4*)(out + (size_t)p * ND);
  dst[threadIdx.x] = src[threadIdx.x];
  if (threadIdx.x == 0) out[(size_t)NP * ND + p] = (float)v;
}

extern "C" void kernel_launch(void* const* d_in, const int* in_sizes, int n_in,
                              void* d_out, int out_size, void* d_ws, size_t ws_size,
                              hipStream_t stream) {
  const float* prompt = (const float*)d_in[0];
  const float* clip = (const float*)d_in[1];
  float* out = (float*)d_out;

  // workspace layout
  size_t off = 0;
  unsigned long long* best = (unsigned long long*)d_ws;
  off += (size_t)NP * 8;
  float* b2 = (float*)((char*)d_ws + off);
  off += (size_t)NV * 4;
  off = (off + 255) & ~(size_t)255;
  __bf16* Ap = (__bf16*)((char*)d_ws + off);
  off += (size_t)NP * KPH * 2;                 // 2 MiB
  __bf16* Bp = (__bf16*)((char*)d_ws + off);
  off += (size_t)NV * KPH * 2;                 // ~96.5 MiB
  const size_t need = off;

  if (ws_size >= need) {
    hipMemsetAsync(best, 0xFF, (size_t)NP * 8, stream);
    pack_rows_k<<<NP / 4, 256, 0, stream>>>(prompt, Ap, nullptr, NP);
    pack_rows_k<<<NV / 4, 256, 0, stream>>>(clip, Bp, b2, NV);
    dim3 grid(NP / 256, NV / 256);  // (4, 193): x = M fastest -> B-panel reuse
    gemm_argmin_k<<<grid, 512, 0, stream>>>(Ap, Bp, b2, best);
    gather_k<<<NP, 128, 0, stream>>>(best, clip, out);
  } else {
    // fallback: exact fp32, needs only the 8 KiB `best` array
    hipMemsetAsync(best, 0xFF, (size_t)NP * 8, stream);
    dim3 grid(NV / 256, NP);
    naive_argmin_k<<<grid, 256, 0, stream>>>(prompt, clip, best);
    gather_k<<<NP, 128, 0, stream>>>(best, clip, out);
  }
}

// Round 5
// 283.154 us; speedup vs baseline: 1.7727x; 1.0338x over previous
//
#include <hip/hip_runtime.h>
#include <stdint.h>

#define NP 1024
#define NV 49408
#define ND 512
// A,B packed: [row][hi(512)|lo(512)] bf16 -> physical K=1024 (2048 B/row).
// Logical K=1536 (3-term split): k<512: ah*bh ; 512..1023: al*bh ; 1024..1535: ah*bl
//   A phys tile: t & 15          (ah, al, ah)
//   B phys tile: t<8 ? t : t-8   (bh, bh, bl)
#define NT 24      // K-tiles of 64
#define NI 12      // iterations (2 K-tiles each)

typedef __attribute__((ext_vector_type(8))) __bf16 bf16x8;
typedef __attribute__((ext_vector_type(4))) float f32x4;

__device__ inline unsigned long long pack_sv(float s, unsigned v) {
  unsigned u = __float_as_uint(s);
  u = (u & 0x80000000u) ? ~u : (u | 0x80000000u);  // orderable map
  return ((unsigned long long)u << 32) | (unsigned long long)v;
}

// Split each f32 row into bf16 hi/lo halves, layout [row][hi(512)|lo(512)];
// optionally emit exact f32 sum of squares per row.
__global__ __launch_bounds__(256) void pack_rows_k(const float* __restrict__ src,
                                                   __bf16* __restrict__ dst,
                                                   float* __restrict__ sumsq,
                                                   int nrows) {
  int lane = threadIdx.x & 63;
  int row = blockIdx.x * 4 + (threadIdx.x >> 6);
  if (row >= nrows) return;
  const float* r = src + (size_t)row * ND + lane * 8;
  float4 x0 = *(const float4*)r;
  float4 x1 = *(const float4*)(r + 4);
  float xs[8] = {x0.x, x0.y, x0.z, x0.w, x1.x, x1.y, x1.z, x1.w};
  bf16x8 hi, lo;
  float ss = 0.f;
#pragma unroll
  for (int j = 0; j < 8; ++j) {
    float x = xs[j];
    ss += x * x;
    __bf16 h = (__bf16)x;
    hi[j] = h;
    lo[j] = (__bf16)(x - (float)h);   // exact residual, then RTNE to bf16
  }
  __bf16* drow = dst + (size_t)row * 1024 + lane * 8;
  *(bf16x8*)drow = hi;
  *(bf16x8*)(drow + 512) = lo;
  if (sumsq != nullptr) {
#pragma unroll
    for (int m = 1; m < 64; m <<= 1) ss += __shfl_xor(ss, m);
    if (lane == 0) sumsq[row] = ss;
  }
}

// ---- 256x256 4-fat-phase deep-pipelined GEMM + fused argmin ----------------
// LDS (bytes), buf p = [p*65536, +65536): A.KH0 @+0, A.KH1 @+16384,
// B.KH0 @+32768, B.KH1 @+49152. Each half = 256 rows x 32 cols bf16 (16 KB),
// 16B-slot permutation q = (row>>1)*8 + (row&1)*4 + ((c16+(row>>1))&3)
// (conflict-free fragment reads). Stage side uses the inverse mapping on the
// global source so the LDS dest stays linear (rule #21).

__device__ __attribute__((always_inline)) static inline
void stage_half(const char* src, char* dst) {
#pragma unroll
  for (int i = 0; i < 2; ++i)
    __builtin_amdgcn_global_load_lds(
        (const __attribute__((address_space(1))) void*)(src + i * 262144),
        (__attribute__((address_space(3))) void*)(dst + i * 8192), 16, 0, 0);
}

// Phase PI: reads half RD[PI], stages the region that died last phase
// (consumed 3 phases later). vmcnt(8) = counted drain of the 3-deep,
// 4-loads/phase pipeline (never 0 in the loop): completes phase p-2's loads,
// whose data is read at phase p+1.
template <int PI>
__device__ __attribute__((always_inline)) static inline
void phase_op(f32x4 (&acc)[8][4], const char* aBase, const char* bBase,
              const char* srcA, int aK, const char* srcB, int bK, char* st) {
  constexpr int RD[4]   = {0, 16384, 65536, 81920};
  constexpr int ADST[4] = {81920, 0, 16384, 65536};
  constexpr int BDST[4] = {114688, 32768, 49152, 98304};
  bf16x8 a[8], b[4];
#pragma unroll
  for (int m = 0; m < 8; ++m) a[m] = *(const bf16x8*)(aBase + RD[PI] + m * 1024);
#pragma unroll
  for (int n = 0; n < 4; ++n) b[n] = *(const bf16x8*)(bBase + RD[PI] + n * 1024);
  stage_half(srcA + aK, st + ADST[PI]);
  stage_half(srcB + bK, st + BDST[PI]);
  asm volatile("" ::: "memory");
  __builtin_amdgcn_s_barrier();
  asm volatile("" ::: "memory");
  __builtin_amdgcn_s_setprio(1);
#pragma unroll
  for (int m = 0; m < 8; ++m)
#pragma unroll
    for (int n = 0; n < 4; ++n)
      acc[m][n] = __builtin_amdgcn_mfma_f32_16x16x32_bf16(a[m], b[n], acc[m][n], 0, 0, 0);
  __builtin_amdgcn_s_setprio(0);
  asm volatile("s_waitcnt vmcnt(8)" ::: "memory");
  __builtin_amdgcn_s_barrier();
  asm volatile("" ::: "memory");
}

__global__ __launch_bounds__(512, 2) void gemm_argmin_k(const __bf16* __restrict__ A,
                                                        const __bf16* __restrict__ B,
                                                        const float* __restrict__ b2,
                                                        unsigned long long* __restrict__ best) {
  __shared__ __align__(16) char lds[131072];
  const int tid = threadIdx.x;
  const int lane = tid & 63;
  const int wid = tid >> 6;   // 0..7
  const int wm = wid >> 2;    // 2 wave-rows (128 rows each)
  const int wn = wid & 3;     // 4 wave-cols (64 cols each)
  const int bm = blockIdx.x * 256;
  const int bn = blockIdx.y * 256;

  const int r = lane & 15, g = lane >> 4;
  const int rh = r >> 1;
  const int laneByte = rh * 128 + (r & 1) * 64 + (((g + rh) & 3) << 4);
  const char* aBase = (const char*)lds + wm * 8192 + laneByte;
  const char* bBase = (const char*)lds + 32768 + wn * 4096 + laneByte;

  // stage-side lane mapping (inverse of the slot permutation)
  const int srow0 = ((tid >> 3) << 1) | ((tid >> 2) & 1);
  const int sc16 = ((tid & 3) - (tid >> 3)) & 3;
  const char* srcA = (const char*)A + (size_t)(bm + srow0) * 2048 + sc16 * 16;
  const char* srcB = (const char*)B + (size_t)(bn + srow0) * 2048 + sc16 * 16;
  char* st = (char*)lds + tid * 16;

  f32x4 acc[8][4] = {};

  auto aByte = [](int t) { return (t & 15) * 128; };           // ah,al,ah
  auto bByte = [](int t) { return (t < 8 ? t : t - 8) * 128; };// bh,bh,bl

  // prologue: t0.KH0, t0.KH1, t1.KH0 (12 loads/thread), drain oldest 4
  stage_half(srcA + aByte(0),      st + 0);
  stage_half(srcB + bByte(0),      st + 32768);
  stage_half(srcA + aByte(0) + 64, st + 16384);
  stage_half(srcB + bByte(0) + 64, st + 49152);
  stage_half(srcA + aByte(1),      st + 65536);
  stage_half(srcB + bByte(1),      st + 98304);
  asm volatile("s_waitcnt vmcnt(8)" ::: "memory");
  __builtin_amdgcn_s_barrier();
  asm volatile("" ::: "memory");

  // stage stream per iter: p0:t1.KH1  p1:t2.KH0  p2:t2.KH1  p3:t3.KH0
#pragma unroll 1
  for (int it = 0; it < NI; ++it) {
    const int t1 = 2 * it + 1;
    int t2 = 2 * it + 2; if (t2 >= NT) t2 -= NT;  // tail wraps: dead re-stage
    int t3 = 2 * it + 3; if (t3 >= NT) t3 -= NT;
    phase_op<0>(acc, aBase, bBase, srcA, aByte(t1) + 64, srcB, bByte(t1) + 64, st);
    phase_op<1>(acc, aBase, bBase, srcA, aByte(t2),      srcB, bByte(t2),      st);
    phase_op<2>(acc, aBase, bBase, srcA, aByte(t2) + 64, srcB, bByte(t2) + 64, st);
    phase_op<3>(acc, aBase, bBase, srcA, aByte(t3),      srcB, bByte(t3),      st);
  }

  // epilogue: fused argmin. C/D map: col = lane&15, row = (lane>>4)*4 + reg.
  float bb[4];
#pragma unroll
  for (int n = 0; n < 4; ++n) bb[n] = b2[bn + wn * 64 + n * 16 + r];
#pragma unroll
  for (int m = 0; m < 8; ++m) {
#pragma unroll
    for (int reg = 0; reg < 4; ++reg) {
      unsigned long long pk = ~0ull;
#pragma unroll
      for (int n = 0; n < 4; ++n) {
        float s = bb[n] - 2.0f * acc[m][n][reg];
        unsigned long long cand = pack_sv(s, (unsigned)(bn + wn * 64 + n * 16 + r));
        pk = (cand < pk) ? cand : pk;
      }
#pragma unroll
      for (int msk = 1; msk < 16; msk <<= 1) {
        unsigned long long o = __shfl_xor(pk, msk);
        pk = (o < pk) ? o : pk;
      }
      if (r == 0) atomicMin(&best[bm + wm * 128 + m * 16 + g * 4 + reg], pk);
    }
  }
}

// Fallback (small ws): exact fp32 squared distance, fused argmin.
__global__ __launch_bounds__(256) void naive_argmin_k(const float* __restrict__ A,
                                                      const float* __restrict__ B,
                                                      unsigned long long* __restrict__ best) {
  __shared__ float arow[ND];
  int p = blockIdx.y;
  unsigned v = blockIdx.x * 256 + threadIdx.x;
  for (int i = threadIdx.x; i < ND; i += 256) arow[i] = A[(size_t)p * ND + i];
  __syncthreads();
  const float4* br = (const float4*)(B + (size_t)v * ND);
  float s = 0.f;
#pragma unroll 4
  for (int i = 0; i < ND / 4; ++i) {
    float4 b = br[i];
    const float4 a = *(const float4*)&arow[i * 4];
    float d0 = a.x - b.x, d1 = a.y - b.y, d2 = a.z - b.z, d3 = a.w - b.w;
    s += d0 * d0 + d1 * d1 + d2 * d2 + d3 * d3;
  }
  unsigned long long pk = pack_sv(s, v);
#pragma unroll
  for (int msk = 1; msk < 64; msk <<= 1) {
    unsigned long long o = __shfl_xor(pk, msk);
    pk = (o < pk) ? o : pk;
  }
  if ((threadIdx.x & 63) == 0) atomicMin(&best[p], pk);
}

// Gather winning rows + ids (ids written as float, d_out is read as flat f32).
__global__ __launch_bounds__(128) void gather_k(const unsigned long long* __restrict__ best,
                                                const float* __restrict__ clip,
                                                float* __restrict__ out) {
  int p = blockIdx.x;
  unsigned long long pk = best[p];
  unsigned v = (unsigned)(pk & 0xffffffffull);
  const float4* src = (const float4*)(clip + (size_t)v * ND);
  float4* dst = (float4*)(out + (size_t)p * ND);
  dst[threadIdx.x] = src[threadIdx.x];
  if (threadIdx.x == 0) out[(size_t)NP * ND + p] = (float)v;
}

extern "C" void kernel_launch(void* const* d_in, const int* in_sizes, int n_in,
                              void* d_out, int out_size, void* d_ws, size_t ws_size,
                              hipStream_t stream) {
  const float* prompt = (const float*)d_in[0];
  const float* clip = (const float*)d_in[1];
  float* out = (float*)d_out;

  // workspace layout
  size_t off = 0;
  unsigned long long* best = (unsigned long long*)d_ws;
  off += (size_t)NP * 8;
  float* b2 = (float*)((char*)d_ws + off);
  off += (size_t)NV * 4;
  off = (off + 255) & ~(size_t)255;
  __bf16* Ap = (__bf16*)((char*)d_ws + off);
  off += (size_t)NP * 1024 * 2;                // 2 MiB  [hi|lo]
  __bf16* Bp = (__bf16*)((char*)d_ws + off);
  off += (size_t)NV * 1024 * 2;                // 96.5 MiB [hi|lo]
  const size_t need = off;

  if (ws_size >= need) {
    hipMemsetAsync(best, 0xFF, (size_t)NP * 8, stream);
    pack_rows_k<<<NP / 4, 256, 0, stream>>>(prompt, Ap, nullptr, NP);
    pack_rows_k<<<NV / 4, 256, 0, stream>>>(clip, Bp, b2, NV);
    dim3 grid(NP / 256, NV / 256);  // (4, 193): x = M fastest -> B-panel reuse
    gemm_argmin_k<<<grid, 512, 0, stream>>>(Ap, Bp, b2, best);
    gather_k<<<NP, 128, 0, stream>>>(best, clip, out);
  } else {
    // fallback: exact fp32, needs only the 8 KiB `best` array
    hipMemsetAsync(best, 0xFF, (size_t)NP * 8, stream);
    dim3 grid(NV / 256, NP);
    naive_argmin_k<<<grid, 256, 0, stream>>>(prompt, clip, best);
    gather_k<<<NP, 128, 0, stream>>>(best, clip, out);
  }
}

// Round 6
// 229.861 us; speedup vs baseline: 2.1837x; 1.2318x over previous
//
#include <hip/hip_runtime.h>
#include <stdint.h>

#define NP 1024
#define NV 49408
#define ND 512
// A,B packed: [row][hi(512)|lo(512)] bf16 -> physical K=1024 (2048 B/row).
// Logical K=1536 (3-term split): k<512: ah*bh ; 512..1023: al*bh ; 1024..1535: ah*bl
// K-step granularity 32 -> 48 logical tiles:
//   A phys byte = (t & 31) * 64
//   B phys byte = (t & 15) * 64 + (t >= 32 ? 1024 : 0)
#define NTILE 48

typedef __attribute__((ext_vector_type(8))) __bf16 bf16x8;
typedef __attribute__((ext_vector_type(4))) float f32x4;

__device__ inline unsigned long long pack_sv(float s, unsigned v) {
  unsigned u = __float_as_uint(s);
  u = (u & 0x80000000u) ? ~u : (u | 0x80000000u);  // orderable map
  return ((unsigned long long)u << 32) | (unsigned long long)v;
}

// Split each f32 row into bf16 hi/lo halves, layout [row][hi(512)|lo(512)];
// optionally emit exact f32 sum of squares per row.
__global__ __launch_bounds__(256) void pack_rows_k(const float* __restrict__ src,
                                                   __bf16* __restrict__ dst,
                                                   float* __restrict__ sumsq,
                                                   int nrows) {
  int lane = threadIdx.x & 63;
  int row = blockIdx.x * 4 + (threadIdx.x >> 6);
  if (row >= nrows) return;
  const float* r = src + (size_t)row * ND + lane * 8;
  float4 x0 = *(const float4*)r;
  float4 x1 = *(const float4*)(r + 4);
  float xs[8] = {x0.x, x0.y, x0.z, x0.w, x1.x, x1.y, x1.z, x1.w};
  bf16x8 hi, lo;
  float ss = 0.f;
#pragma unroll
  for (int j = 0; j < 8; ++j) {
    float x = xs[j];
    ss += x * x;
    __bf16 h = (__bf16)x;
    hi[j] = h;
    lo[j] = (__bf16)(x - (float)h);   // exact residual, then RTNE to bf16
  }
  __bf16* drow = dst + (size_t)row * 1024 + lane * 8;
  *(bf16x8*)drow = hi;
  *(bf16x8*)(drow + 512) = lo;
  if (sumsq != nullptr) {
#pragma unroll
    for (int m = 1; m < 64; m <<= 1) ss += __shfl_xor(ss, m);
    if (lane == 0) sumsq[row] = ss;
  }
}

// ---- 128x128 tile, BK=32, 4 waves, 3 blocks/CU, depth-2 counted rotation ---
// LDS: 3 regions of 16 KB: region R at R*16384: A half (128x32 bf16, 8 KB)
// @+0, B half @+8192. 16B-slot permutation within a half:
//   q(row,c16) = (row>>1)*8 + (row&1)*4 + ((c16 + (row>>1)) & 3)
// (2-way bank aliasing = free). Stage uses the inverse mapping on the global
// source; LDS dest stays linear (rule #21).
// Rotation: phase p reads region p%3, stages region (p+2)%3 with tile p+2.
// vmcnt(4) at phase end drains phase p-1's 4 loads -> region for p+1 ready.

__device__ __attribute__((always_inline)) static inline
void gll16(const char* src, char* dst) {
  __builtin_amdgcn_global_load_lds(
      (const __attribute__((address_space(1))) void*)src,
      (__attribute__((address_space(3))) void*)dst, 16, 0, 0);
}

template <int R>
__device__ __attribute__((always_inline)) static inline
void phase_op(f32x4 (&acc)[4][4], const char* aBase, const char* bBase,
              const char* sA, const char* sB, char* st) {
  constexpr int RS = (R + 2) % 3;
  // stage next+2 tile (issue-early; region RS was last read at phase p-1)
#pragma unroll
  for (int i = 0; i < 2; ++i) gll16(sA + i * 131072, st + RS * 16384 + i * 4096);
#pragma unroll
  for (int i = 0; i < 2; ++i) gll16(sB + i * 131072, st + RS * 16384 + 8192 + i * 4096);
  // fragment reads for this phase (8 x ds_read_b128)
  bf16x8 a[4], b[4];
#pragma unroll
  for (int m = 0; m < 4; ++m) a[m] = *(const bf16x8*)(aBase + R * 16384 + m * 1024);
#pragma unroll
  for (int n = 0; n < 4; ++n) b[n] = *(const bf16x8*)(bBase + R * 16384 + n * 1024);
  asm volatile("" ::: "memory");
  __builtin_amdgcn_s_barrier();
  asm volatile("" ::: "memory");
  __builtin_amdgcn_s_setprio(1);
#pragma unroll
  for (int m = 0; m < 4; ++m)
#pragma unroll
    for (int n = 0; n < 4; ++n)
      acc[m][n] = __builtin_amdgcn_mfma_f32_16x16x32_bf16(a[m], b[n], acc[m][n], 0, 0, 0);
  __builtin_amdgcn_s_setprio(0);
  asm volatile("s_waitcnt vmcnt(4)" ::: "memory");
  __builtin_amdgcn_s_barrier();
  asm volatile("" ::: "memory");
}

__global__ __launch_bounds__(256, 3) void gemm_argmin_k(const __bf16* __restrict__ A,
                                                        const __bf16* __restrict__ B,
                                                        const float* __restrict__ b2,
                                                        unsigned long long* __restrict__ best) {
  __shared__ __align__(16) char lds[49152];
  const int tid = threadIdx.x;
  const int lane = tid & 63;
  const int wid = tid >> 6;   // 0..3
  const int wm = wid >> 1;    // 2 wave-rows (64 rows each)
  const int wn = wid & 1;     // 2 wave-cols (64 cols each)

  // T1 XCD-chunked swizzle (3088 % 8 == 0 -> bijective): all 8 M-blocks of a
  // B-panel land on one XCD -> panel L2-resident, staged loads are L2 hits.
  const int d = blockIdx.x;
  const int o = (d & 7) * 386 + (d >> 3);
  const int bm = (o & 7) * 128;
  const int bn = (o >> 3) * 128;

  const int r = lane & 15, g = lane >> 4;
  const int rh = r >> 1;
  const int laneByte = rh * 128 + (r & 1) * 64 + (((g + rh) & 3) << 4);
  const char* aBase = (const char*)lds + wm * 4096 + laneByte;
  const char* bBase = (const char*)lds + 8192 + wn * 4096 + laneByte;

  // stage-side lane mapping (inverse of the slot permutation), rows 0..63 (+64 for i=1)
  const int srow0 = 2 * (tid >> 3) + ((tid >> 2) & 1);
  const int sc16 = ((tid & 3) - (tid >> 3)) & 3;
  const char* srcA = (const char*)A + (size_t)(bm + srow0) * 2048 + sc16 * 16;
  const char* srcB = (const char*)B + (size_t)(bn + srow0) * 2048 + sc16 * 16;
  char* st = (char*)lds + tid * 16;

  f32x4 acc[4][4] = {};

  auto aByte = [](int t) { return (t & 31) * 64; };
  auto bByte = [](int t) { return (t & 15) * 64 + (t >= 32 ? 1024 : 0); };

  // prologue: stage tiles 0,1 into regions 0,1; drain tile 0 (vmcnt(4))
#pragma unroll
  for (int i = 0; i < 2; ++i) gll16(srcA + aByte(0) + i * 131072, st + i * 4096);
#pragma unroll
  for (int i = 0; i < 2; ++i) gll16(srcB + bByte(0) + i * 131072, st + 8192 + i * 4096);
#pragma unroll
  for (int i = 0; i < 2; ++i) gll16(srcA + aByte(1) + i * 131072, st + 16384 + i * 4096);
#pragma unroll
  for (int i = 0; i < 2; ++i) gll16(srcB + bByte(1) + i * 131072, st + 16384 + 8192 + i * 4096);
  asm volatile("s_waitcnt vmcnt(4)" ::: "memory");
  __builtin_amdgcn_s_barrier();
  asm volatile("" ::: "memory");

#pragma unroll 1
  for (int it = 0; it < 16; ++it) {
    const int p = 3 * it;
    int t2 = p + 2; if (t2 >= NTILE) t2 -= NTILE;   // tail wraps: dead re-stage
    int t3 = p + 3; if (t3 >= NTILE) t3 -= NTILE;
    int t4 = p + 4; if (t4 >= NTILE) t4 -= NTILE;
    phase_op<0>(acc, aBase, bBase, srcA + aByte(t2), srcB + bByte(t2), st);
    phase_op<1>(acc, aBase, bBase, srcA + aByte(t3), srcB + bByte(t3), st);
    phase_op<2>(acc, aBase, bBase, srcA + aByte(t4), srcB + bByte(t4), st);
  }

  // epilogue: fused argmin. C/D map: col = lane&15, row = (lane>>4)*4 + reg.
  float bb[4];
#pragma unroll
  for (int n = 0; n < 4; ++n) bb[n] = b2[bn + wn * 64 + n * 16 + r];
#pragma unroll
  for (int m = 0; m < 4; ++m) {
#pragma unroll
    for (int reg = 0; reg < 4; ++reg) {
      unsigned long long pk = ~0ull;
#pragma unroll
      for (int n = 0; n < 4; ++n) {
        float s = bb[n] - 2.0f * acc[m][n][reg];
        unsigned long long cand = pack_sv(s, (unsigned)(bn + wn * 64 + n * 16 + r));
        pk = (cand < pk) ? cand : pk;
      }
#pragma unroll
      for (int msk = 1; msk < 16; msk <<= 1) {
        unsigned long long o2 = __shfl_xor(pk, msk);
        pk = (o2 < pk) ? o2 : pk;
      }
      if (r == 0) atomicMin(&best[bm + wm * 64 + m * 16 + g * 4 + reg], pk);
    }
  }
}

// Fallback (small ws): exact fp32 squared distance, fused argmin.
__global__ __launch_bounds__(256) void naive_argmin_k(const float* __restrict__ A,
                                                      const float* __restrict__ B,
                                                      unsigned long long* __restrict__ best) {
  __shared__ float arow[ND];
  int p = blockIdx.y;
  unsigned v = blockIdx.x * 256 + threadIdx.x;
  for (int i = threadIdx.x; i < ND; i += 256) arow[i] = A[(size_t)p * ND + i];
  __syncthreads();
  const float4* br = (const float4*)(B + (size_t)v * ND);
  float s = 0.f;
#pragma unroll 4
  for (int i = 0; i < ND / 4; ++i) {
    float4 b = br[i];
    const float4 a = *(const float4*)&arow[i * 4];
    float d0 = a.x - b.x, d1 = a.y - b.y, d2 = a.z - b.z, d3 = a.w - b.w;
    s += d0 * d0 + d1 * d1 + d2 * d2 + d3 * d3;
  }
  unsigned long long pk = pack_sv(s, v);
#pragma unroll
  for (int msk = 1; msk < 64; msk <<= 1) {
    unsigned long long o = __shfl_xor(pk, msk);
    pk = (o < pk) ? o : pk;
  }
  if ((threadIdx.x & 63) == 0) atomicMin(&best[p], pk);
}

// Gather winning rows + ids (ids written as float, d_out is read as flat f32).
__global__ __launch_bounds__(128) void gather_k(const unsigned long long* __restrict__ best,
                                                const float* __restrict__ clip,
                                                float* __restrict__ out) {
  int p = blockIdx.x;
  unsigned long long pk = best[p];
  unsigned v = (unsigned)(pk & 0xffffffffull);
  const float4* src = (const float4*)(clip + (size_t)v * ND);
  float4* dst = (float4*)(out + (size_t)p * ND);
  dst[threadIdx.x] = src[threadIdx.x];
  if (threadIdx.x == 0) out[(size_t)NP * ND + p] = (float)v;
}

extern "C" void kernel_launch(void* const* d_in, const int* in_sizes, int n_in,
                              void* d_out, int out_size, void* d_ws, size_t ws_size,
                              hipStream_t stream) {
  const float* prompt = (const float*)d_in[0];
  const float* clip = (const float*)d_in[1];
  float* out = (float*)d_out;

  // workspace layout
  size_t off = 0;
  unsigned long long* best = (unsigned long long*)d_ws;
  off += (size_t)NP * 8;
  float* b2 = (float*)((char*)d_ws + off);
  off += (size_t)NV * 4;
  off = (off + 255) & ~(size_t)255;
  __bf16* Ap = (__bf16*)((char*)d_ws + off);
  off += (size_t)NP * 1024 * 2;                // 2 MiB  [hi|lo]
  __bf16* Bp = (__bf16*)((char*)d_ws + off);
  off += (size_t)NV * 1024 * 2;                // 96.5 MiB [hi|lo]
  const size_t need = off;

  if (ws_size >= need) {
    hipMemsetAsync(best, 0xFF, (size_t)NP * 8, stream);
    pack_rows_k<<<NP / 4, 256, 0, stream>>>(prompt, Ap, nullptr, NP);
    pack_rows_k<<<NV / 4, 256, 0, stream>>>(clip, Bp, b2, NV);
    gemm_argmin_k<<<dim3(8 * 386), 256, 0, stream>>>(Ap, Bp, b2, best);
    gather_k<<<NP, 128, 0, stream>>>(best, clip, out);
  } else {
    // fallback: exact fp32, needs only the 8 KiB `best` array
    hipMemsetAsync(best, 0xFF, (size_t)NP * 8, stream);
    dim3 grid(NV / 256, NP);
    naive_argmin_k<<<grid, 256, 0, stream>>>(prompt, clip, best);
    gather_k<<<NP, 128, 0, stream>>>(best, clip, out);
  }
}